// Round 15
// baseline (263.831 us; speedup 1.0000x reference)
//
#include <hip/hip_runtime.h>
#include <hip/hip_bf16.h>

#define EPS 1e-5f

typedef __attribute__((ext_vector_type(8))) short bf16x8;
typedef __attribute__((ext_vector_type(4))) float f32x4;
typedef __attribute__((ext_vector_type(4))) unsigned short u16x4;
typedef __attribute__((ext_vector_type(8))) unsigned short u16x8;

#define WAITVM8 asm volatile("s_waitcnt vmcnt(8)" ::: "memory")
#define WAITVM4 asm volatile("s_waitcnt vmcnt(4)" ::: "memory")
#define WAITVM2 asm volatile("s_waitcnt vmcnt(2)" ::: "memory")
#define WAITVM0 asm volatile("s_waitcnt vmcnt(0)" ::: "memory")
#define BAR()   __builtin_amdgcn_s_barrier()

// ---- async global->LDS, 16B per lane, linear dest (wave-uniform base + lane*16)
__device__ __forceinline__ void gld_lds16(const void* g, void* l) {
    __builtin_amdgcn_global_load_lds(
        (const __attribute__((address_space(1))) unsigned int*)g,
        (__attribute__((address_space(3))) unsigned int*)l, 16, 0, 0);
}

// ---- GEMM step macros (R9 schedule: 1 barrier + 1 counted vm-wait per K32).
#define RD8(RA, RB, SEL) do {                                                  \
    const int _b = (SEL) * 8192;                                               \
    _Pragma("unroll") for (int _i = 0; _i < 4; ++_i)                           \
        RA[_i] = *reinterpret_cast<const bf16x8*>(&lA[_b + aoff + _i * 512]);  \
    _Pragma("unroll") for (int _j = 0; _j < 4; ++_j)                           \
        RB[_j] = *reinterpret_cast<const bf16x8*>(&lB[_b + boff + _j * 512]);  \
} while (0)

#define RD4(RA4, SEL) do {                                                     \
    const int _b = (SEL) * 8192;                                               \
    _Pragma("unroll") for (int _i = 0; _i < 4; ++_i)                           \
        RA4[_i] = *reinterpret_cast<const bf16x8*>(                            \
            &lA[_b + aoff + (_i + 4) * 512]);                                  \
} while (0)

#define MFQ(RA, RB, I0) do {                                                   \
    _Pragma("unroll") for (int _i = 0; _i < 4; ++_i)                           \
    _Pragma("unroll") for (int _j = 0; _j < 4; ++_j)                           \
        acc[(I0) + _i][_j] = __builtin_amdgcn_mfma_f32_16x16x32_bf16(          \
            RA[_i], RB[_j], acc[(I0) + _i][_j], 0, 0, 0);                      \
} while (0)

#define STEP(CA0, CA4, CB, NA0, NB, SELT, STAGE_STMT, WAIT_STMT, DORD) do {    \
    RD4(CA4, (SELT));                                                          \
    STAGE_STMT;                                                                \
    __builtin_amdgcn_s_setprio(1); MFQ(CA0, CB, 0);                            \
    __builtin_amdgcn_s_setprio(0);                                             \
    WAIT_STMT;                                                                 \
    BAR();                                                                     \
    if (DORD) RD8(NA0, NB, ((SELT) + 1) & 3);                                  \
    __builtin_amdgcn_s_setprio(1); MFQ(CA4, CB, 4);                            \
    __builtin_amdgcn_s_setprio(0);                                             \
} while (0)

// =============== conv3x3 implicit-GEMM device body (R9 schedule) =============
template<int HIN, int WIN, int NTOT>
__device__ __forceinline__ void conv_dev(
    int bid, int tid,
    __hip_bfloat16* lA, __hip_bfloat16* lB,
    const __hip_bfloat16* __restrict__ xt,  // [B][HIN][WIN][256]
    const __hip_bfloat16* __restrict__ wt,  // [256][9][256]
    const float* __restrict__ g, const float* __restrict__ bb,
    const float* __restrict__ mm_, const float* __restrict__ vv,
    __hip_bfloat16* __restrict__ y)         // NHWC: [NTOT][256]
{
    constexpr int HOUT = HIN - 2, WOUT = WIN - 2, POUT = HOUT * WOUT;
    const int n0  = bid * 256;
    const int wid = tid >> 6, lane = tid & 63;
    const int wr = wid >> 2, wc = wid & 3;

    const int arow = tid >> 2;                       // 0..127
    const int seg  = (tid & 3) ^ ((tid >> 3) & 3);   // inverse slot-swizzle

    const size_t wbase0 = (size_t)arow * 2304 + seg * 8;
    const size_t wbase1 = (size_t)(arow + 128) * 2304 + seg * 8;

    int nr0 = n0 + arow;       if (nr0 > NTOT - 1) nr0 = NTOT - 1;
    int nr1 = n0 + arow + 128; if (nr1 > NTOT - 1) nr1 = NTOT - 1;
    int b0 = nr0 / POUT, p0 = nr0 % POUT, oy0 = p0 / WOUT, ox0 = p0 % WOUT;
    int b1 = nr1 / POUT, p1 = nr1 % POUT, oy1 = p1 / WOUT, ox1 = p1 % WOUT;
    const size_t xbase0 = (((size_t)b0 * HIN + oy0) * WIN + ox0) * 256 + seg * 8;
    const size_t xbase1 = (((size_t)b1 * HIN + oy1) * WIN + ox1) * 256 + seg * 8;

    auto stage = [&](int c0, int j, int sel) {
        char* a0 = (char*)lA + sel * 16384 + wid * 1024;
        char* b0p = (char*)lB + sel * 16384 + wid * 1024;
        const int woff = j * 256 + c0;
        gld_lds16(wt + wbase0 + woff, a0);
        gld_lds16(wt + wbase1 + woff, a0 + 8192);
        const int xoff = ((j / 3) * WIN + (j % 3)) * 256 + c0;
        gld_lds16(xt + xbase0 + xoff, b0p);
        gld_lds16(xt + xbase1 + xoff, b0p + 8192);
    };

    f32x4 acc[8][4];
#pragma unroll
    for (int i = 0; i < 8; ++i)
#pragma unroll
        for (int j = 0; j < 4; ++j)
            acc[i][j] = f32x4{0.f, 0.f, 0.f, 0.f};

    const int l15 = lane & 15, l16 = lane >> 4;
    const int slot = l16 ^ ((l15 >> 1) & 3);
    const int aoff = (wr * 128 + l15) * 32 + slot * 8;
    const int boff = (wc * 64  + l15) * 32 + slot * 8;

    bf16x8 pA0[4], pA4[4], pB[4], qA0[4], qA4[4], qB[4];

    stage(0, 0, 0); stage(0, 1, 1); stage(0, 2, 2);
    int js = 3, c0s = 0;  // stage cursor for step t+3
    WAITVM8; BAR();
    RD8(pA0, pB, 0);

#define ADVC do { ++js; if (js == 9) { js = 0; c0s += 32; } } while (0)
    for (int tt = 0; tt < 17; ++tt) {
        STEP(pA0, pA4, pB, qA0, qB, 0, stage(c0s, js, 3), WAITVM8, true); ADVC;
        STEP(qA0, qA4, qB, pA0, pB, 1, stage(c0s, js, 0), WAITVM8, true); ADVC;
        STEP(pA0, pA4, pB, qA0, qB, 2, stage(c0s, js, 1), WAITVM8, true); ADVC;
        STEP(qA0, qA4, qB, pA0, pB, 3, stage(c0s, js, 2), WAITVM8, true); ADVC;
    }
    STEP(pA0, pA4, pB, qA0, qB, 0, stage(c0s, js, 3), WAITVM8, true);
    STEP(qA0, qA4, qB, pA0, pB, 1, (void)0,           WAITVM4, true);
    STEP(pA0, pA4, pB, qA0, qB, 2, (void)0,           WAITVM0, true);
    STEP(qA0, qA4, qB, pA0, pB, 3, (void)0,           (void)0, false);
#undef ADVC

#pragma unroll
    for (int i = 0; i < 8; ++i) {
        const int co_b = wr * 128 + i * 16 + l16 * 4;
        float sc[4], sh[4];
#pragma unroll
        for (int r = 0; r < 4; ++r) {
            sc[r] = g[co_b + r] * rsqrtf(vv[co_b + r] + EPS);
            sh[r] = bb[co_b + r] - mm_[co_b + r] * sc[r];
        }
#pragma unroll
        for (int jj = 0; jj < 4; ++jj) {
            const int n = n0 + wc * 64 + jj * 16 + l15;
            if (n < NTOT) {
                u16x4 o;
#pragma unroll
                for (int r = 0; r < 4; ++r) {
                    const float v = fmaxf(fmaf(acc[i][jj][r], sc[r], sh[r]), 0.f);
                    __hip_bfloat16 hv = __float2bfloat16(v);
                    o[r] = *reinterpret_cast<unsigned short*>(&hv);
                }
                *reinterpret_cast<u16x4*>(&y[(size_t)n * 256 + co_b]) = o;
            }
        }
    }
}

// ---------------- conv_both: search blocks 0..420, kernel blocks 421..433 ----
__global__ __launch_bounds__(512, 2) void conv_both(
    const __hip_bfloat16* __restrict__ xt_s, const __hip_bfloat16* __restrict__ wt_cs,
    const float* __restrict__ g2, const float* __restrict__ b2,
    const float* __restrict__ m2, const float* __restrict__ v2,
    __hip_bfloat16* __restrict__ y2,
    const __hip_bfloat16* __restrict__ xt_k, const __hip_bfloat16* __restrict__ wt_ck,
    const float* __restrict__ g1, const float* __restrict__ b1,
    const float* __restrict__ m1, const float* __restrict__ v1,
    __hip_bfloat16* __restrict__ y1)
{
    __shared__ __align__(16) __hip_bfloat16 lA[4 * 8192];
    __shared__ __align__(16) __hip_bfloat16 lB[4 * 8192];
    if (blockIdx.x < 421)
        conv_dev<31, 31, 107648>(blockIdx.x, threadIdx.x, lA, lB,
                                 xt_s, wt_cs, g2, b2, m2, v2, y2);
    else
        conv_dev<7, 7, 3200>(blockIdx.x - 421, threadIdx.x, lA, lB,
                             xt_k, wt_ck, g1, b1, m1, v1, y1);
}

// =============== merged pre-pass kernel ======================================
__device__ __forceinline__ void nhwc_body(
    const float* __restrict__ x, __hip_bfloat16* __restrict__ xt, int P,
    int bx, int b, float* t /* [256*33] */)
{
    const int p0 = bx * 32;
    const float* xb = x + (size_t)b * 256 * P;
    const int pl = threadIdx.x & 31, cg = threadIdx.x >> 5;
#pragma unroll
    for (int it = 0; it < 32; ++it) {
        int c = cg + it * 8, p = p0 + pl;
        t[c * 33 + pl] = (p < P) ? xb[(size_t)c * P + p] : 0.f;
    }
    __syncthreads();
    const int p = threadIdx.x >> 3, l8 = threadIdx.x & 7;
    if (p0 + p < P) {
        __hip_bfloat16* xo = xt + ((size_t)b * P + p0 + p) * 256;
#pragma unroll
        for (int j = 0; j < 4; ++j) {
            const int c0 = j * 64 + l8 * 8;
            u16x8 o;
#pragma unroll
            for (int r = 0; r < 8; ++r) {
                __hip_bfloat16 hv = __float2bfloat16(t[(c0 + r) * 33 + p]);
                o[r] = *reinterpret_cast<unsigned short*>(&hv);
            }
            *reinterpret_cast<u16x8*>(&xo[c0]) = o;
        }
    }
}

__global__ __launch_bounds__(256) void prepass(
    const float* __restrict__ w_ck, __hip_bfloat16* __restrict__ wt_ck,
    const float* __restrict__ w_cs, __hip_bfloat16* __restrict__ wt_cs,
    const float* __restrict__ w_h1, __hip_bfloat16* __restrict__ wh1,
    const float* __restrict__ kernel, __hip_bfloat16* __restrict__ xt_k,
    const float* __restrict__ search, __hip_bfloat16* __restrict__ xt_s)
{
    __shared__ float t[256 * 33];
    const int bid = blockIdx.x;
    if (bid < 512) {
        const float* w = (bid < 256) ? w_ck : w_cs;
        __hip_bfloat16* wt = (bid < 256) ? wt_ck : wt_cs;
        const int co = bid & 255, ci = threadIdx.x;
        const float* wp = w + (size_t)co * 2304 + (size_t)ci * 9;
        __hip_bfloat16* wo = wt + (size_t)co * 2304 + ci;
#pragma unroll
        for (int j = 0; j < 9; ++j)
            wo[(size_t)j * 256] = __float2bfloat16(wp[j]);
    } else if (bid < 768) {
        const int i = (bid - 512) * 256 + threadIdx.x;
        wh1[i] = __float2bfloat16(w_h1[i]);
    } else if (bid < 1024) {
        const int idx = bid - 768;
        nhwc_body(kernel, xt_k, 49, idx & 1, idx >> 1, t);
    } else {
        const int idx = bid - 1024;
        nhwc_body(search, xt_s, 961, idx % 31, idx / 31, t);
    }
}

// ======= fused xcorr (5-row strip) + head layer1 MFMA + BN/ReLU + layer2 =====
// Phase 1 (v2): 512 thr = 128 channel-PAIRS x 4 px-quarters (px0=6q, width 7,
// overlap columns written twice with bit-identical values). float2 math over
// the channel pair -> half the FMA instructions (v_pk_fma_f32 eligible) and
// perfectly balanced: 875 float2-FMAs per thread (was 1875 scalar worst-wave).
// Phases 2/3 unchanged from R14 (head GEMM from featL + fused layer-2).
__global__ __launch_bounds__(512) void xcorr_head(
    const __hip_bfloat16* __restrict__ s,   // y2 [B][841][256]
    const __hip_bfloat16* __restrict__ k,   // y1 [B][25][256]
    const __hip_bfloat16* __restrict__ w1,  // [256][256] bf16
    const float* __restrict__ g, const float* __restrict__ bb,
    const float* __restrict__ mm_, const float* __restrict__ vv,
    const float* __restrict__ w2,           // [10][256]
    const float* __restrict__ b2v,          // [10]
    float* __restrict__ out)                // [B][10][25][25]
{
    const int st = blockIdx.x, b = blockIdx.y;
    const int py0 = st * 5;
    const int tid = threadIdx.x;

    __shared__ __align__(16) __hip_bfloat16 featL[128 * 264];  // 67.6 KB
    __shared__ __align__(16) __hip_bfloat16 lA[3 * 8192];      // 48 KB

    // ---------------- phase 1: xcorr -> featL (float2 over channel pairs) ----
    {
        const int pr = tid & 127;          // channel pair: ch 2pr, 2pr+1
        const int q  = tid >> 7;           // px quarter (wave-uniform)
        const int px0 = q * 6;             // 0,6,12,18; width 7 covers 0..24

        const ushort2* sp = reinterpret_cast<const ushort2*>(
                                s + (size_t)b * 841 * 256) + pr;
        const ushort2* kp = reinterpret_cast<const ushort2*>(
                                k + (size_t)b * 25 * 256) + pr;

        auto cvt2 = [](ushort2 u) {
            unsigned int w0 = (unsigned int)u.x << 16, w1 = (unsigned int)u.y << 16;
            float2 r;
            r.x = *reinterpret_cast<float*>(&w0);
            r.y = *reinterpret_cast<float*>(&w1);
            return r;
        };

        float2 kv[25];
#pragma unroll
        for (int i = 0; i < 25; ++i) kv[i] = cvt2(kp[(size_t)i * 128]);

        float2 acc[5][7];
#pragma unroll
        for (int p = 0; p < 5; ++p)
#pragma unroll
            for (int x = 0; x < 7; ++x) acc[p][x] = float2{0.f, 0.f};

#pragma unroll
        for (int r = 0; r < 9; ++r) {
            float2 srow[11];
            const ushort2* srp = sp + (size_t)(py0 + r) * 29 * 128;
#pragma unroll
            for (int c = 0; c < 11; ++c)
                srow[c] = cvt2(srp[(size_t)(px0 + c) * 128]);
#pragma unroll
            for (int p = 0; p < 5; ++p) {
                if (r >= p && r - p <= 4) {   // constant after unroll
                    const int ky = r - p;
#pragma unroll
                    for (int kx = 0; kx < 5; ++kx) {
                        const float2 kvv = kv[ky * 5 + kx];
#pragma unroll
                        for (int x = 0; x < 7; ++x) {
                            acc[p][x].x = fmaf(srow[x + kx].x, kvv.x, acc[p][x].x);
                            acc[p][x].y = fmaf(srow[x + kx].y, kvv.y, acc[p][x].y);
                        }
                    }
                }
            }
        }

        ushort2* fL2 = reinterpret_cast<ushort2*>(featL);
#pragma unroll
        for (int p = 0; p < 5; ++p)
#pragma unroll
            for (int x = 0; x < 7; ++x) {
                const int px = px0 + x;
                __hip_bfloat16 h0 = __float2bfloat16(acc[p][x].x);
                __hip_bfloat16 h1 = __float2bfloat16(acc[p][x].y);
                ushort2 o;
                o.x = *reinterpret_cast<unsigned short*>(&h0);
                o.y = *reinterpret_cast<unsigned short*>(&h1);
                fL2[(p * 25 + px) * 132 + pr] = o;
            }
    }
    __syncthreads();

    // ---------------- phase 2: head GEMM ----------------
    const int wid = tid >> 6, lane = tid & 63;
    const int wr = wid >> 2, wc = wid & 3;       // wave tile 128co x 32px
    const int l15 = lane & 15, l16 = lane >> 4;
    const int seg  = (lane & 3) ^ ((lane >> 3) & 3);
    const int slot = l16 ^ ((l15 >> 1) & 3);
    const int aoff = (wr * 128 + l15) * 32 + slot * 8;

    auto stageA = [&](int c0, int sel) {
        char* dst = (char*)lA + sel * 16384 + wid * 2048;  // 32 rows x 64B/wave
        const size_t r0 = (size_t)(wid * 32 + (lane >> 2)) * 256;
        gld_lds16(w1 + r0 + c0 + seg * 8, dst);
        gld_lds16(w1 + r0 + 16 * 256 + c0 + seg * 8, dst + 1024);
    };

    f32x4 acc[8][2];
#pragma unroll
    for (int i = 0; i < 8; ++i) {
        acc[i][0] = f32x4{0.f, 0.f, 0.f, 0.f};
        acc[i][1] = f32x4{0.f, 0.f, 0.f, 0.f};
    }

#define RDH(AF, BF, SEL, C0) do {                                              \
    const int _b = (SEL) * 8192;                                               \
    _Pragma("unroll") for (int _i = 0; _i < 8; ++_i)                           \
        AF[_i] = *reinterpret_cast<const bf16x8*>(&lA[_b + aoff + _i * 512]);  \
    _Pragma("unroll") for (int _j = 0; _j < 2; ++_j)                           \
        BF[_j] = *reinterpret_cast<const bf16x8*>(                             \
            &featL[(wc * 32 + _j * 16 + l15) * 264 + (C0) + l16 * 8]);         \
} while (0)

#define MFH(AF, BF) do {                                                       \
    __builtin_amdgcn_s_setprio(1);                                             \
    _Pragma("unroll") for (int _i = 0; _i < 8; ++_i)                           \
    _Pragma("unroll") for (int _j = 0; _j < 2; ++_j)                           \
        acc[_i][_j] = __builtin_amdgcn_mfma_f32_16x16x32_bf16(                 \
            AF[_i], BF[_j], acc[_i][_j], 0, 0, 0);                             \
    __builtin_amdgcn_s_setprio(0);                                             \
} while (0)

    {
        bf16x8 af[8], bf[2];
        stageA(0, 0); stageA(32, 1);
        WAITVM2; BAR();
        RDH(af, bf, 0, 0);   stageA(64, 2);  MFH(af, bf);   // t=0
        WAITVM2; BAR();
        RDH(af, bf, 1, 32);  stageA(96, 0);  MFH(af, bf);   // t=1
        WAITVM2; BAR();
        RDH(af, bf, 2, 64);  stageA(128, 1); MFH(af, bf);   // t=2
        WAITVM2; BAR();
        RDH(af, bf, 0, 96);  stageA(160, 2); MFH(af, bf);   // t=3
        WAITVM2; BAR();
        RDH(af, bf, 1, 128); stageA(192, 0); MFH(af, bf);   // t=4
        WAITVM2; BAR();
        RDH(af, bf, 2, 160); stageA(224, 1); MFH(af, bf);   // t=5
        WAITVM2; BAR();
        RDH(af, bf, 0, 192);                 MFH(af, bf);   // t=6
        WAITVM0; BAR();
        RDH(af, bf, 1, 224);                 MFH(af, bf);   // t=7
    }
#undef RDH
#undef MFH

    // ---------------- phase 3: BN + ReLU + layer-2 -> out ----------------
    __syncthreads();                 // all GEMM LDS reads done
    float* lw   = (float*)lA;        // [10][256] w2 + [10] b2
    float* lred = lw + 2816;         // [4 wc][2 jj][16 l15][10 o]
    for (int t = tid; t < 2560; t += 512) lw[t] = w2[t];
    if (tid < 10) lw[2560 + tid] = b2v[tid];
    __syncthreads();

    float p[2][10];
#pragma unroll
    for (int jj = 0; jj < 2; ++jj)
#pragma unroll
        for (int o = 0; o < 10; ++o) p[jj][o] = 0.f;

#pragma unroll
    for (int i = 0; i < 8; ++i) {
        const int co_b = wr * 128 + i * 16 + l16 * 4;
        float sc[4], sh[4];
#pragma unroll
        for (int r = 0; r < 4; ++r) {
            sc[r] = g[co_b + r] * rsqrtf(vv[co_b + r] + EPS);
            sh[r] = bb[co_b + r] - mm_[co_b + r] * sc[r];
        }
        float w4[10][4];
#pragma unroll
        for (int o = 0; o < 10; ++o) {
            f32x4 wv = *reinterpret_cast<const f32x4*>(&lw[o * 256 + co_b]);
#pragma unroll
            for (int r = 0; r < 4; ++r) w4[o][r] = wv[r];
        }
#pragma unroll
        for (int jj = 0; jj < 2; ++jj) {
            float hv[4];
#pragma unroll
            for (int r = 0; r < 4; ++r)
                hv[r] = fmaxf(fmaf(acc[i][jj][r], sc[r], sh[r]), 0.f);
#pragma unroll
            for (int o = 0; o < 10; ++o)
#pragma unroll
                for (int r = 0; r < 4; ++r)
                    p[jj][o] = fmaf(hv[r], w4[o][r], p[jj][o]);
        }
    }

#pragma unroll
    for (int jj = 0; jj < 2; ++jj)
#pragma unroll
        for (int o = 0; o < 10; ++o) {
            float v = p[jj][o];
            v += __shfl_xor(v, 16, 64);
            v += __shfl_xor(v, 32, 64);
            p[jj][o] = v;
        }

    if (wr == 0 && l16 == 0) {
#pragma unroll
        for (int jj = 0; jj < 2; ++jj)
#pragma unroll
            for (int o = 0; o < 10; ++o)
                lred[((wc * 2 + jj) * 16 + l15) * 10 + o] = p[jj][o];
    }
    __syncthreads();
    if (wr == 1) {
#pragma unroll
        for (int jj = 0; jj < 2; ++jj) {
            const int n = wc * 32 + jj * 16 + l15;
            if (n < 125) {
                const int py = py0 + n / 25, pxc = n % 25;
#pragma unroll
                for (int t = 0; t < 3; ++t) {
                    const int o = l16 + 4 * t;
                    if (o < 10) {
                        float v = p[jj][o]
                                + lred[((wc * 2 + jj) * 16 + l15) * 10 + o]
                                + lw[2560 + o];
                        out[(((size_t)b * 10 + o) * 25 + py) * 25 + pxc] = v;
                    }
                }
            }
        }
    }
}

extern "C" void kernel_launch(void* const* d_in, const int* in_sizes, int n_in,
                              void* d_out, int out_size, void* d_ws, size_t ws_size,
                              hipStream_t stream) {
    const float* kernel = (const float*)d_in[0];   // [128,256,7,7]
    const float* search = (const float*)d_in[1];   // [128,256,31,31]
    const float* w_ck   = (const float*)d_in[2];
    const float* g1 = (const float*)d_in[3];
    const float* b1 = (const float*)d_in[4];
    const float* m1 = (const float*)d_in[5];
    const float* v1 = (const float*)d_in[6];
    const float* w_cs   = (const float*)d_in[7];
    const float* g2 = (const float*)d_in[8];
    const float* b2 = (const float*)d_in[9];
    const float* m2 = (const float*)d_in[10];
    const float* v2 = (const float*)d_in[11];
    const float* w_h1   = (const float*)d_in[12];
    const float* g3 = (const float*)d_in[13];
    const float* b3 = (const float*)d_in[14];
    const float* m3 = (const float*)d_in[15];
    const float* v3 = (const float*)d_in[16];
    const float* w_h2   = (const float*)d_in[17];
    const float* b_h2   = (const float*)d_in[18];

    float* out = (float*)d_out;

    __hip_bfloat16* ws = (__hip_bfloat16*)d_ws;
    __hip_bfloat16* y1    = ws;
    __hip_bfloat16* y2    = ws + (size_t)819200;
    __hip_bfloat16* wt_ck = ws + (size_t)28377088;
    __hip_bfloat16* wt_cs = ws + (size_t)28966912;
    __hip_bfloat16* wh1   = ws + (size_t)29556736;
    __hip_bfloat16* xt_k  = ws + (size_t)29622272;
    __hip_bfloat16* xt_s  = ws + (size_t)31227904;

    (void)in_sizes; (void)n_in; (void)out_size; (void)ws_size;

    // 1) merged pre-passes (wt transposes, w_h1 cast, NHWC converts)
    prepass<<<4992, 256, 0, stream>>>(w_ck, wt_ck, w_cs, wt_cs, w_h1, wh1,
                                      kernel, xt_k, search, xt_s);

    // 2) both convs in one dispatch: search (421 tiles) + kernel branch (13)
    conv_both<<<434, 512, 0, stream>>>(xt_s, wt_cs, g2, b2, m2, v2, y2,
                                       xt_k, wt_ck, g1, b1, m1, v1, y1);

    // 3) fused xcorr + head (layer1 MFMA + BN + ReLU + layer2) -> out
    xcorr_head<<<dim3(5, 128), 512, 0, stream>>>(
        y2, y1, wh1, g3, b3, m3, v3, w_h2, b_h2, out);
}